// Round 3
// baseline (441.058 us; speedup 1.0000x reference)
//
#include <hip/hip_runtime.h>

typedef unsigned short u16;
typedef __bf16 bf16x8 __attribute__((ext_vector_type(8)));
typedef float f32x4 __attribute__((ext_vector_type(4)));

__device__ __forceinline__ float b2f(u16 u) {
    unsigned int x = ((unsigned int)u) << 16;
    return __builtin_bit_cast(float, x);
}
__device__ __forceinline__ u16 f2b(float f) {
    unsigned int u = __builtin_bit_cast(unsigned int, f);
    unsigned int r = (u + 0x7FFFu + ((u >> 16) & 1u)) >> 16;
    return (u16)r;
}
__device__ __forceinline__ unsigned int pack2(float a, float b) {
    return (unsigned int)f2b(a) | ((unsigned int)f2b(b) << 16);
}
__device__ __forceinline__ float fast_rcp(float x) { return __builtin_amdgcn_rcpf(x); }
__device__ __forceinline__ float fast_tanh(float x) {
    float e = __expf(2.f * x);
    return 1.f - 2.f * fast_rcp(e + 1.f);
}
__device__ __forceinline__ float fast_sig(float x) {
    float e = __expf(-x);
    return fast_rcp(1.f + e);
}

// cast f32 -> bf16, 4 elems/thread
__global__ void k_cast(const float* __restrict__ s, u16* __restrict__ d, int n4) {
    int i = blockIdx.x * 256 + threadIdx.x;
    if (i >= n4) return;
    float4 a = ((const float4*)s)[i];
    uint2 p;
    p.x = pack2(a.x, a.y);
    p.y = pack2(a.z, a.w);
    ((uint2*)d)[i] = p;
}

// Transpose+cast four 512x512 f32 matrices: dst[n][k] = bf16(src[k][n])
__global__ void k_tr4(const float* s0, const float* s1, const float* s2, const float* s3,
                      u16* d0, u16* d1, u16* d2, u16* d3) {
    __shared__ float tile[32][33];
    const float* s; u16* d;
    switch (blockIdx.z) {
        case 0: s = s0; d = d0; break;
        case 1: s = s1; d = d1; break;
        case 2: s = s2; d = d2; break;
        default: s = s3; d = d3; break;
    }
    int bx = blockIdx.x * 32, by = blockIdx.y * 32;
    int tx = threadIdx.x, ty = threadIdx.y;  // (32,8)
    for (int i = 0; i < 32; i += 8) tile[ty + i][tx] = s[(by + ty + i) * 512 + bx + tx];
    __syncthreads();
    for (int i = 0; i < 32; i += 8) d[(bx + ty + i) * 512 + by + tx] = f2b(tile[tx][ty + i]);
}

// Build x = concat(init_i, lstm_in) as [32][32][512] bf16 from f32 sources. 4 elems/thread.
__global__ void k_xfull(const float* __restrict__ lstm_in, const float* __restrict__ init_i,
                        u16* __restrict__ xfull) {
    int idx = blockIdx.x * 256 + threadIdx.x;  // 131072 chunks of 4
    int c = idx & 127;
    int t = (idx >> 7) & 31;
    int b = idx >> 12;
    const float4* src = (t == 0) ? ((const float4*)init_i) + c
                                 : ((const float4*)lstm_in) + ((b * 31 + (t - 1)) * 128 + c);
    float4 a = *src;
    uint2 p;
    p.x = pack2(a.x, a.y);
    p.y = pack2(a.z, a.w);
    ((uint2*)xfull)[idx] = p;
}

// C[M,GN] = A[M,512](bf16) * Bt[GN,512](bf16)^T  [+ bias1[n]+bias2[n]]
// grid: (GN/64, M/64), block 256. BF16OUT: C u16 else f32.
template <bool BF16OUT>
__launch_bounds__(256)
__global__ void k_gemm(const u16* __restrict__ A, const u16* __restrict__ Bt,
                       void* __restrict__ Cv, int GN,
                       const float* __restrict__ bias1, const float* __restrict__ bias2) {
    __shared__ u16 As[64][40];  // +8 pad: 2-way bank aliasing only (free)
    __shared__ u16 Bs[64][40];
    int m0 = blockIdx.y * 64, n0 = blockIdx.x * 64;
    int tid = threadIdx.x;
    int lane = tid & 63, w = tid >> 6;
    int wm = w >> 1, wn = w & 1;
    int l15 = lane & 15, quad = lane >> 4;
    f32x4 acc[2][2] = {};
    int ar = tid >> 2, ac = (tid & 3) * 8;
    const u16* Ap = A + (m0 + ar) * 512 + ac;
    const u16* Bp = Bt + (n0 + ar) * 512 + ac;
    for (int kt = 0; kt < 16; ++kt) {
        uint4 av = *(const uint4*)(Ap + kt * 32);
        uint4 bv = *(const uint4*)(Bp + kt * 32);
        __syncthreads();
        *(uint4*)&As[ar][ac] = av;
        *(uint4*)&Bs[ar][ac] = bv;
        __syncthreads();
        bf16x8 a0 = *(const bf16x8*)&As[wm * 32 + l15][quad * 8];
        bf16x8 a1 = *(const bf16x8*)&As[wm * 32 + 16 + l15][quad * 8];
        bf16x8 b0 = *(const bf16x8*)&Bs[wn * 32 + l15][quad * 8];
        bf16x8 b1 = *(const bf16x8*)&Bs[wn * 32 + 16 + l15][quad * 8];
        acc[0][0] = __builtin_amdgcn_mfma_f32_16x16x32_bf16(a0, b0, acc[0][0], 0, 0, 0);
        acc[0][1] = __builtin_amdgcn_mfma_f32_16x16x32_bf16(a0, b1, acc[0][1], 0, 0, 0);
        acc[1][0] = __builtin_amdgcn_mfma_f32_16x16x32_bf16(a1, b0, acc[1][0], 0, 0, 0);
        acc[1][1] = __builtin_amdgcn_mfma_f32_16x16x32_bf16(a1, b1, acc[1][1], 0, 0, 0);
    }
    for (int ai = 0; ai < 2; ++ai)
        for (int bi = 0; bi < 2; ++bi) {
            int row = m0 + wm * 32 + ai * 16 + quad * 4;
            int col = n0 + wn * 32 + bi * 16 + l15;
            float bias = 0.f;
            if (bias1) bias = bias1[col] + bias2[col];
            if constexpr (BF16OUT) {
                u16* C = (u16*)Cv;
                for (int r = 0; r < 4; ++r) C[(row + r) * GN + col] = f2b(acc[ai][bi][r] + bias);
            } else {
                float* C = (float*)Cv;
                for (int r = 0; r < 4; ++r) C[(row + r) * GN + col] = acc[ai][bi][r] + bias;
            }
        }
}

__global__ void k_init(const float* __restrict__ init_h, const float* __restrict__ init_c,
                       u16* __restrict__ h_ws, float* __restrict__ c_ws) {
    int idx = blockIdx.x * 256 + threadIdx.x;  // 32*512
    int k = idx & 511;
    h_ws[idx] = f2b(init_h[k]);
    c_ws[idx] = init_c[k];
}

// One LSTM step. grid 64 blocks x 256. Block bid owns k-columns [bid*8, bid*8+8)
// of all four gates (column-aligned), so the c/h update is block-local.
// xw already holds x@w_ih^T + b_ih + b_hh (f32).
__launch_bounds__(256)
__global__ void k_step(const u16* __restrict__ h_in, u16* __restrict__ h_out,
                       float* __restrict__ c_ws,
                       const u16* __restrict__ w_hh, const float* __restrict__ xw,
                       u16* __restrict__ query, int t) {
    __shared__ u16 Ah[32][264];  // h tile, K-phase of 256, +8 pad
    __shared__ u16 Bw[32][264];  // 32 selected w_hh rows
    __shared__ float gl[32][33];
    int tid = threadIdx.x;
    int k0 = blockIdx.x * 8;
    int lane = tid & 63, w = tid >> 6;
    int mi = w >> 1, ni = w & 1;
    int l15 = lane & 15, quad = lane >> 4;
    int row = tid >> 3, seg = tid & 7;
    int j_row = (row >> 3) * 512 + k0 + (row & 7);  // gate*512 + k for local col `row`
    f32x4 acc = {};
    for (int ph = 0; ph < 2; ++ph) {
        const uint4* hsrc = (const uint4*)(h_in + row * 512 + ph * 256 + seg * 32);
        const uint4* wsrc = (const uint4*)(w_hh + j_row * 512 + ph * 256 + seg * 32);
        uint4 hv[4], wv[4];
        for (int i = 0; i < 4; ++i) { hv[i] = hsrc[i]; wv[i] = wsrc[i]; }
        __syncthreads();
        for (int i = 0; i < 4; ++i) {
            *(uint4*)&Ah[row][seg * 32 + i * 8] = hv[i];
            *(uint4*)&Bw[row][seg * 32 + i * 8] = wv[i];
        }
        __syncthreads();
        for (int kc = 0; kc < 8; ++kc) {
            bf16x8 a = *(const bf16x8*)&Ah[mi * 16 + l15][kc * 32 + quad * 8];
            bf16x8 b = *(const bf16x8*)&Bw[ni * 16 + l15][kc * 32 + quad * 8];
            acc = __builtin_amdgcn_mfma_f32_16x16x32_bf16(a, b, acc, 0, 0, 0);
        }
    }
    {
        int r0 = mi * 16 + quad * 4, col = ni * 16 + l15;
        for (int r = 0; r < 4; ++r) gl[r0 + r][col] = acc[r];
    }
    __syncthreads();
    // update: thread -> (b, kl); local col = gate*8 + kl
    int b = tid >> 3, kl = tid & 7, kg = k0 + kl;
    const float* xwp = xw + ((b << 5) + t) * 2048;
    float gi = gl[b][0 * 8 + kl] + xwp[0 * 512 + kg];
    float gf = gl[b][1 * 8 + kl] + xwp[1 * 512 + kg];
    float gg = gl[b][2 * 8 + kl] + xwp[2 * 512 + kg];
    float go = gl[b][3 * 8 + kl] + xwp[3 * 512 + kg];
    float cold = c_ws[b * 512 + kg];
    float cnew = fast_sig(gf) * cold + fast_sig(gi) * fast_tanh(gg);
    float h = fast_sig(go) * fast_tanh(cnew);
    c_ws[b * 512 + kg] = cnew;
    u16 hb = f2b(h);
    h_out[b * 512 + kg] = hb;
    query[((b << 5) + t) * 512 + kg] = hb;
}

// score[b,t,n] = sum_h tanh(feat[b,n,h] + q[b,t,h]) * v[h];  feat bf16, q f32, v f32
// mode 0: write raw scores to out (f32). mode 1: masked softmax -> out (f32 norm)
__launch_bounds__(256)
__global__ void k_score(const u16* __restrict__ feat, const float* __restrict__ q,
                        const float* __restrict__ v, const int* __restrict__ mem_sizes,
                        float* __restrict__ outp, int mode) {
    __shared__ float qs[512];
    __shared__ float vs[512];
    __shared__ float sc[128];
    int bt = blockIdx.x;
    int b = bt >> 5;
    int tid = threadIdx.x;
    qs[tid] = q[bt * 512 + tid];
    qs[tid + 256] = q[bt * 512 + 256 + tid];
    vs[tid] = v[tid];
    vs[tid + 256] = v[tid + 256];
    __syncthreads();
    int lane = tid & 63, w = tid >> 6;
    int h0 = lane * 8;
    float qv[8], vv[8];
#pragma unroll
    for (int i = 0; i < 8; ++i) { qv[i] = qs[h0 + i]; vv[i] = vs[h0 + i]; }
    const u16* fb = feat + (size_t)b * 128 * 512;
    for (int i = 0; i < 32; ++i) {
        int n = w * 32 + i;
        uint4 fv = *(const uint4*)(fb + n * 512 + h0);
        float fr[8];
        fr[0] = b2f((u16)(fv.x & 0xFFFF)); fr[1] = b2f((u16)(fv.x >> 16));
        fr[2] = b2f((u16)(fv.y & 0xFFFF)); fr[3] = b2f((u16)(fv.y >> 16));
        fr[4] = b2f((u16)(fv.z & 0xFFFF)); fr[5] = b2f((u16)(fv.z >> 16));
        fr[6] = b2f((u16)(fv.w & 0xFFFF)); fr[7] = b2f((u16)(fv.w >> 16));
        float a = 0.f;
#pragma unroll
        for (int jj = 0; jj < 8; ++jj) a += fast_tanh(fr[jj] + qv[jj]) * vv[jj];
        for (int off = 1; off < 64; off <<= 1) a += __shfl_xor(a, off);
        if (lane == 0) sc[n] = a;
    }
    __syncthreads();
    if (mode == 0) {
        if (tid < 128) outp[bt * 128 + tid] = sc[tid];
    } else {
        if (tid < 64) {
            int ms = mem_sizes[b];
            float s0 = (tid < ms) ? sc[tid] : -1e30f;
            float s1 = (tid + 64 < ms) ? sc[tid + 64] : -1e30f;
            float m = fmaxf(s0, s1);
            for (int off = 1; off < 64; off <<= 1) m = fmaxf(m, __shfl_xor(m, off));
            float e0 = __expf(s0 - m), e1 = __expf(s1 - m);
            float s = e0 + e1;
            for (int off = 1; off < 64; off <<= 1) s += __shfl_xor(s, off);
            float r = fast_rcp(s);
            outp[bt * 128 + tid] = e0 * r;
            outp[bt * 128 + tid + 64] = e1 * r;
        }
    }
}

// nq[b,t,h] = sum_n norm[b,t,n] * feat[b,n,h]   (feat bf16, out bf16)
__launch_bounds__(256)
__global__ void k_nquery(const float* __restrict__ norm, const u16* __restrict__ feat,
                         u16* __restrict__ nq) {
    __shared__ float ns[128];
    int bt = blockIdx.x;
    int b = bt >> 5;
    int tid = threadIdx.x;
    if (tid < 128) ns[tid] = norm[bt * 128 + tid];
    __syncthreads();
    const u16* fb = feat + (size_t)b * 128 * 512;
    float a0 = 0.f, a1 = 0.f;
    int h0 = tid * 2;
    for (int n = 0; n < 128; ++n) {
        float f = ns[n];
        unsigned int pv = *(const unsigned int*)(fb + n * 512 + h0);
        a0 += f * b2f((u16)(pv & 0xFFFF));
        a1 += f * b2f((u16)(pv >> 16));
    }
    nq[bt * 512 + h0] = f2b(a0);
    nq[bt * 512 + h0 + 1] = f2b(a1);
}

extern "C" void kernel_launch(void* const* d_in, const int* in_sizes, int n_in,
                              void* d_out, int out_size, void* d_ws, size_t ws_size,
                              hipStream_t stream) {
    (void)in_sizes; (void)n_in; (void)out_size; (void)ws_size;
    const float* attn_mem = (const float*)d_in[0];
    const int* mem_sizes = (const int*)d_in[1];
    const float* lstm_in = (const float*)d_in[2];
    const float* init_h = (const float*)d_in[3];
    const float* init_c = (const float*)d_in[4];
    const float* init_i = (const float*)d_in[5];
    const float* w_ih = (const float*)d_in[6];
    const float* w_hh = (const float*)d_in[7];
    const float* b_ih = (const float*)d_in[8];
    const float* b_hh = (const float*)d_in[9];
    const float* attn_wm = (const float*)d_in[10];
    const float* attn_wq = (const float*)d_in[11];
    const float* attn_v = (const float*)d_in[12];
    const float* hop_wm = (const float*)d_in[13];
    const float* hop_wq = (const float*)d_in[14];
    const float* hop_v = (const float*)d_in[15];
    float* out = (float*)d_out;

    char* ws = (char*)d_ws;
    size_t off = 0;
    auto alloc = [&](size_t bytes) {
        void* p = ws + off;
        off += (bytes + 255) & ~(size_t)255;
        return p;
    };
    // ~24.3 MB total
    u16* amem_bf = (u16*)alloc(4096 * 512 * 2);   // 4MB; reused later: norm + nq
    u16* xfull_bf = (u16*)alloc(1024 * 512 * 2);  // 1MB \ region B (3MB); reused as qbuf (2MB)
    u16* wih_bf = (u16*)alloc(2048 * 512 * 2);    // 2MB /
    u16* whh_bf = (u16*)alloc(2048 * 512 * 2);    // 2MB
    u16* WmT_hop = (u16*)alloc(512 * 512 * 2);
    u16* WmT_attn = (u16*)alloc(512 * 512 * 2);
    u16* WqT_hop = (u16*)alloc(512 * 512 * 2);
    u16* WqT_attn = (u16*)alloc(512 * 512 * 2);
    float* xw = (float*)alloc(1024 * 2048 * 4);   // 8MB; first 4MB reused as attn_feat
    u16* hop_feat = (u16*)alloc(4096 * 512 * 2);  // 4MB
    u16* query = (u16*)alloc(1024 * 512 * 2);     // 1MB
    u16* hbuf0 = (u16*)alloc(32 * 512 * 2);
    u16* hbuf1 = (u16*)alloc(32 * 512 * 2);
    float* c_ws = (float*)alloc(32 * 512 * 4);
    // aliases (all strictly ordered on `stream`):
    float* norm = (float*)amem_bf;                       // 512KB (amem dead after feat GEMMs)
    u16* nq = (u16*)((char*)amem_bf + 1024 * 1024);      // 1MB, disjoint from norm
    float* qbuf = (float*)xfull_bf;                      // 2MB (xfull/wih dead after xw GEMM)
    u16* attn_feat = (u16*)xw;                           // 4MB (xw dead after LSTM steps)

    k_cast<<<2048, 256, 0, stream>>>(attn_mem, amem_bf, 524288);
    k_cast<<<1024, 256, 0, stream>>>(w_ih, wih_bf, 262144);
    k_cast<<<1024, 256, 0, stream>>>(w_hh, whh_bf, 262144);
    k_xfull<<<512, 256, 0, stream>>>(lstm_in, init_i, xfull_bf);
    k_tr4<<<dim3(16, 16, 4), dim3(32, 8), 0, stream>>>(attn_wm, hop_wm, hop_wq, attn_wq,
                                                       WmT_attn, WmT_hop, WqT_hop, WqT_attn);
    k_gemm<false><<<dim3(32, 16), 256, 0, stream>>>(xfull_bf, wih_bf, xw, 2048, b_ih, b_hh);
    k_gemm<true><<<dim3(8, 64), 256, 0, stream>>>(amem_bf, WmT_hop, hop_feat, 512, nullptr, nullptr);
    k_init<<<64, 256, 0, stream>>>(init_h, init_c, hbuf0, c_ws);
    for (int t = 0; t < 32; ++t) {
        const u16* hin = (t & 1) ? hbuf1 : hbuf0;
        u16* hout = (t & 1) ? hbuf0 : hbuf1;
        k_step<<<64, 256, 0, stream>>>(hin, hout, c_ws, whh_bf, xw, query, t);
    }
    k_gemm<true><<<dim3(8, 64), 256, 0, stream>>>(amem_bf, WmT_attn, attn_feat, 512, nullptr, nullptr);
    k_gemm<false><<<dim3(8, 16), 256, 0, stream>>>(query, WqT_hop, qbuf, 512, nullptr, nullptr);
    k_score<<<1024, 256, 0, stream>>>(hop_feat, qbuf, hop_v, mem_sizes, norm, 1);
    k_nquery<<<1024, 256, 0, stream>>>(norm, hop_feat, nq);
    k_gemm<false><<<dim3(8, 16), 256, 0, stream>>>(nq, WqT_attn, qbuf, 512, nullptr, nullptr);
    k_score<<<1024, 256, 0, stream>>>(attn_feat, qbuf, attn_v, nullptr, out, 0);
}

// Round 4
// 375.352 us; speedup vs baseline: 1.1751x; 1.1751x over previous
//
#include <hip/hip_runtime.h>

typedef unsigned short u16;
typedef __bf16 bf16x8 __attribute__((ext_vector_type(8)));
typedef float f32x4 __attribute__((ext_vector_type(4)));

__device__ __forceinline__ float b2f(u16 u) {
    unsigned int x = ((unsigned int)u) << 16;
    return __builtin_bit_cast(float, x);
}
__device__ __forceinline__ u16 f2b(float f) {
    unsigned int u = __builtin_bit_cast(unsigned int, f);
    unsigned int r = (u + 0x7FFFu + ((u >> 16) & 1u)) >> 16;
    return (u16)r;
}
__device__ __forceinline__ unsigned int pack2(float a, float b) {
    return (unsigned int)f2b(a) | ((unsigned int)f2b(b) << 16);
}
__device__ __forceinline__ float fast_rcp(float x) { return __builtin_amdgcn_rcpf(x); }
__device__ __forceinline__ float fast_tanh(float x) {
    float e = __expf(2.f * x);
    return 1.f - 2.f * fast_rcp(e + 1.f);
}
__device__ __forceinline__ float fast_sig(float x) {
    float e = __expf(-x);
    return fast_rcp(1.f + e);
}

// ---------------- fused prep: casts + xfull + 4x transpose + bar zero -------
// blocks [0,2048): amem cast  [2048,3072): wih  [3072,4096): whh
// [4096,4608): xfull          [4608,5632): tr4 (16x16x4)
__launch_bounds__(256)
__global__ void k_prep(const float* __restrict__ attn_mem, u16* __restrict__ amem_bf,
                       const float* __restrict__ w_ih, u16* __restrict__ wih_bf,
                       const float* __restrict__ w_hh, u16* __restrict__ whh_bf,
                       const float* __restrict__ lstm_in, const float* __restrict__ init_i,
                       u16* __restrict__ xfull,
                       const float* s0, const float* s1, const float* s2, const float* s3,
                       u16* d0, u16* d1, u16* d2, u16* d3,
                       unsigned int* __restrict__ bar) {
    __shared__ float tile[32][33];
    int bid = blockIdx.x;
    int tid = threadIdx.x;
    if (bid == 0 && tid == 0)
        __hip_atomic_store(bar, 0u, __ATOMIC_RELAXED, __HIP_MEMORY_SCOPE_AGENT);
    if (bid < 4096) {
        const float* s;
        u16* d;
        int i;
        if (bid < 2048) { s = attn_mem; d = amem_bf; i = bid * 256 + tid; }
        else if (bid < 3072) { s = w_ih; d = wih_bf; i = (bid - 2048) * 256 + tid; }
        else { s = w_hh; d = whh_bf; i = (bid - 3072) * 256 + tid; }
        float4 a = ((const float4*)s)[i];
        uint2 p;
        p.x = pack2(a.x, a.y);
        p.y = pack2(a.z, a.w);
        ((uint2*)d)[i] = p;
    } else if (bid < 4608) {
        int idx = (bid - 4096) * 256 + tid;  // 131072 chunks of 4
        int c = idx & 127;
        int t = (idx >> 7) & 31;
        int b = idx >> 12;
        const float4* src = (t == 0) ? ((const float4*)init_i) + c
                                     : ((const float4*)lstm_in) + ((b * 31 + (t - 1)) * 128 + c);
        float4 a = *src;
        uint2 p;
        p.x = pack2(a.x, a.y);
        p.y = pack2(a.z, a.w);
        ((uint2*)xfull)[idx] = p;
    } else {
        int local = bid - 4608;
        int z = local >> 8, rem = local & 255;
        int by = (rem >> 4) * 32, bx = (rem & 15) * 32;
        const float* s;
        u16* d;
        switch (z) {
            case 0: s = s0; d = d0; break;
            case 1: s = s1; d = d1; break;
            case 2: s = s2; d = d2; break;
            default: s = s3; d = d3; break;
        }
        int tx = tid & 31, ty = tid >> 5;  // (32,8)
        for (int i = 0; i < 32; i += 8) tile[ty + i][tx] = s[(by + ty + i) * 512 + bx + tx];
        __syncthreads();
        for (int i = 0; i < 32; i += 8) d[(bx + ty + i) * 512 + by + tx] = f2b(tile[tx][ty + i]);
    }
}

// ---------------- GEMM: C[M,GN] = A[M,512] * Bt[GN,512]^T (+bias) ----------
template <bool BF16OUT>
__launch_bounds__(256)
__global__ void k_gemm(const u16* __restrict__ A, const u16* __restrict__ Bt,
                       void* __restrict__ Cv, int GN,
                       const float* __restrict__ bias1, const float* __restrict__ bias2) {
    __shared__ u16 As[64][40];
    __shared__ u16 Bs[64][40];
    int m0 = blockIdx.y * 64, n0 = blockIdx.x * 64;
    int tid = threadIdx.x;
    int lane = tid & 63, w = tid >> 6;
    int wm = w >> 1, wn = w & 1;
    int l15 = lane & 15, quad = lane >> 4;
    f32x4 acc[2][2] = {};
    int ar = tid >> 2, ac = (tid & 3) * 8;
    const u16* Ap = A + (m0 + ar) * 512 + ac;
    const u16* Bp = Bt + (n0 + ar) * 512 + ac;
    for (int kt = 0; kt < 16; ++kt) {
        uint4 av = *(const uint4*)(Ap + kt * 32);
        uint4 bv = *(const uint4*)(Bp + kt * 32);
        __syncthreads();
        *(uint4*)&As[ar][ac] = av;
        *(uint4*)&Bs[ar][ac] = bv;
        __syncthreads();
        bf16x8 a0 = *(const bf16x8*)&As[wm * 32 + l15][quad * 8];
        bf16x8 a1 = *(const bf16x8*)&As[wm * 32 + 16 + l15][quad * 8];
        bf16x8 b0 = *(const bf16x8*)&Bs[wn * 32 + l15][quad * 8];
        bf16x8 b1 = *(const bf16x8*)&Bs[wn * 32 + 16 + l15][quad * 8];
        acc[0][0] = __builtin_amdgcn_mfma_f32_16x16x32_bf16(a0, b0, acc[0][0], 0, 0, 0);
        acc[0][1] = __builtin_amdgcn_mfma_f32_16x16x32_bf16(a0, b1, acc[0][1], 0, 0, 0);
        acc[1][0] = __builtin_amdgcn_mfma_f32_16x16x32_bf16(a1, b0, acc[1][0], 0, 0, 0);
        acc[1][1] = __builtin_amdgcn_mfma_f32_16x16x32_bf16(a1, b1, acc[1][1], 0, 0, 0);
    }
    for (int ai = 0; ai < 2; ++ai)
        for (int bi = 0; bi < 2; ++bi) {
            int row = m0 + wm * 32 + ai * 16 + quad * 4;
            int col = n0 + wn * 32 + bi * 16 + l15;
            float bias = 0.f;
            if (bias1) bias = bias1[col] + bias2[col];
            if constexpr (BF16OUT) {
                u16* C = (u16*)Cv;
                for (int r = 0; r < 4; ++r) C[(row + r) * GN + col] = f2b(acc[ai][bi][r] + bias);
            } else {
                float* C = (float*)Cv;
                for (int r = 0; r < 4; ++r) C[(row + r) * GN + col] = acc[ai][bi][r] + bias;
            }
        }
}

// ---------------- persistent LSTM: all 32 steps, 1 launch ------------------
// 64 blocks x 256. Block bid owns k-cols [bid*8, bid*8+8) of all 4 gates
// (32 w_hh rows, LDS-resident). c-state: 1 value/thread in registers.
// Grid-wide sync via monotone counter (agent-scope atomics + fences).
__launch_bounds__(256, 1)
__global__ void k_lstm(const u16* __restrict__ w_hh_bf, const float* __restrict__ xw,
                       const float* __restrict__ init_h, const float* __restrict__ init_c,
                       u16* __restrict__ query, u16* __restrict__ hbuf,
                       unsigned int* __restrict__ bar) {
    __shared__ u16 Bw[32][520];  // w_hh slice, stride 520 (2-way bank alias: free)
    __shared__ u16 Ah[32][520];  // h tile [batch][512]
    __shared__ float gl[32][33];
    int tid = threadIdx.x;
    int k0 = blockIdx.x * 8;
    int lane = tid & 63, w = tid >> 6;
    int mi = w >> 1, ni = w & 1;
    int l15 = lane & 15, quad = lane >> 4;
    int row = tid >> 3, seg = tid & 7;  // row 0..31, seg 0..7
    // w_hh slice -> LDS (once). Local col r maps to w_hh row (r>>3)*512+k0+(r&7).
    {
        int j = (row >> 3) * 512 + k0 + (row & 7);
        const uint4* src = (const uint4*)(w_hh_bf + j * 512);
        for (int i = 0; i < 8; ++i)
            *(uint4*)&Bw[row][(seg + 8 * i) * 8] = src[seg + 8 * i];
    }
    // h0 (broadcast over batch): stage from init_h
    for (int i = 0; i < 8; ++i) {
        int col = (seg + 8 * i) * 8;
        float4 f0 = *(const float4*)(init_h + col);
        float4 f1 = *(const float4*)(init_h + col + 4);
        uint4 p;
        p.x = pack2(f0.x, f0.y);
        p.y = pack2(f0.z, f0.w);
        p.z = pack2(f1.x, f1.y);
        p.w = pack2(f1.z, f1.w);
        *(uint4*)&Ah[row][col] = p;
    }
    float c = init_c[k0 + seg];  // thread owns (b=row, k=k0+seg)
    __syncthreads();
    for (int t = 0; t < 32; ++t) {
        f32x4 acc = {};
        for (int kc = 0; kc < 16; ++kc) {
            bf16x8 a = *(const bf16x8*)&Ah[mi * 16 + l15][kc * 32 + quad * 8];
            bf16x8 b = *(const bf16x8*)&Bw[ni * 16 + l15][kc * 32 + quad * 8];
            acc = __builtin_amdgcn_mfma_f32_16x16x32_bf16(a, b, acc, 0, 0, 0);
        }
        {
            int r0 = mi * 16 + quad * 4, col = ni * 16 + l15;
            for (int r = 0; r < 4; ++r) gl[r0 + r][col] = acc[r];
        }
        __syncthreads();
        // gate update: thread -> (b=row, kl=seg); local gl col = gate*8+kl
        int b = row, kl = seg, kg = k0 + kl;
        const float* xwp = xw + ((b << 5) + t) * 2048;
        float gi = gl[b][kl] + xwp[kg];
        float gf = gl[b][8 + kl] + xwp[512 + kg];
        float gg = gl[b][16 + kl] + xwp[1024 + kg];
        float go = gl[b][24 + kl] + xwp[1536 + kg];
        float cnew = fast_sig(gf) * c + fast_sig(gi) * fast_tanh(gg);
        c = cnew;
        float h = fast_sig(go) * fast_tanh(cnew);
        u16 hb = f2b(h);
        query[((b << 5) + t) * 512 + kg] = hb;
        if (t < 31) {
            u16* hout = hbuf + (t & 1) * (32 * 512);
            hout[b * 512 + kg] = hb;
            __syncthreads();  // all waves' writes drained (vmcnt0) + gl reads done
            if (tid == 0) {
                __builtin_amdgcn_fence(__ATOMIC_RELEASE, "agent");
                __hip_atomic_fetch_add(bar, 1u, __ATOMIC_RELAXED, __HIP_MEMORY_SCOPE_AGENT);
                unsigned int target = 64u * (unsigned)(t + 1);
                while (__hip_atomic_load(bar, __ATOMIC_RELAXED, __HIP_MEMORY_SCOPE_AGENT) < target)
                    __builtin_amdgcn_s_sleep(1);
                __builtin_amdgcn_fence(__ATOMIC_ACQUIRE, "agent");
            }
            __syncthreads();
            // restage full h(t+1)
            const uint4* src = (const uint4*)(hbuf + (t & 1) * (32 * 512) + row * 512);
            for (int i = 0; i < 8; ++i)
                *(uint4*)&Ah[row][(seg + 8 * i) * 8] = src[seg + 8 * i];
            __syncthreads();
        }
    }
}

// ---------------- fused hop attention: score + masked softmax + weighted sum
// block per (b,t). nq[b,t,h] = sum_n softmax_n(score)[n] * feat[b,n,h]
__launch_bounds__(256)
__global__ void k_hop(const u16* __restrict__ feat, const float* __restrict__ q,
                      const float* __restrict__ v, const int* __restrict__ mem_sizes,
                      u16* __restrict__ nq) {
    __shared__ float qs[512];
    __shared__ float vs[512];
    __shared__ float sc[128];
    __shared__ float ns[128];
    int bt = blockIdx.x;
    int b = bt >> 5;
    int tid = threadIdx.x;
    qs[tid] = q[bt * 512 + tid];
    qs[tid + 256] = q[bt * 512 + 256 + tid];
    vs[tid] = v[tid];
    vs[tid + 256] = v[tid + 256];
    __syncthreads();
    int lane = tid & 63, w = tid >> 6;
    int h0 = lane * 8;
    float qv[8], vv[8];
#pragma unroll
    for (int i = 0; i < 8; ++i) { qv[i] = qs[h0 + i]; vv[i] = vs[h0 + i]; }
    const u16* fb = feat + (size_t)b * 128 * 512;
    for (int i = 0; i < 32; ++i) {
        int n = w * 32 + i;
        uint4 fv = *(const uint4*)(fb + n * 512 + h0);
        float fr[8];
        fr[0] = b2f((u16)(fv.x & 0xFFFF)); fr[1] = b2f((u16)(fv.x >> 16));
        fr[2] = b2f((u16)(fv.y & 0xFFFF)); fr[3] = b2f((u16)(fv.y >> 16));
        fr[4] = b2f((u16)(fv.z & 0xFFFF)); fr[5] = b2f((u16)(fv.z >> 16));
        fr[6] = b2f((u16)(fv.w & 0xFFFF)); fr[7] = b2f((u16)(fv.w >> 16));
        float a = 0.f;
#pragma unroll
        for (int jj = 0; jj < 8; ++jj) a += fast_tanh(fr[jj] + qv[jj]) * vv[jj];
        for (int off = 1; off < 64; off <<= 1) a += __shfl_xor(a, off);
        if (lane == 0) sc[n] = a;
    }
    __syncthreads();
    if (tid < 64) {
        int ms = mem_sizes[b];
        float s0 = (tid < ms) ? sc[tid] : -1e30f;
        float s1 = (tid + 64 < ms) ? sc[tid + 64] : -1e30f;
        float m = fmaxf(s0, s1);
        for (int off = 1; off < 64; off <<= 1) m = fmaxf(m, __shfl_xor(m, off));
        float e0 = __expf(s0 - m), e1 = __expf(s1 - m);
        float s = e0 + e1;
        for (int off = 1; off < 64; off <<= 1) s += __shfl_xor(s, off);
        float r = fast_rcp(s);
        ns[tid] = e0 * r;
        ns[tid + 64] = e1 * r;
    }
    __syncthreads();
    // weighted sum: thread owns cols {2*tid, 2*tid+1}
    float a0 = 0.f, a1 = 0.f;
    int hc = tid * 2;
    for (int n = 0; n < 128; ++n) {
        float f = ns[n];
        unsigned int pv = *(const unsigned int*)(fb + n * 512 + hc);
        a0 += f * b2f((u16)(pv & 0xFFFF));
        a1 += f * b2f((u16)(pv >> 16));
    }
    ((unsigned int*)nq)[bt * 256 + tid] = pack2(a0, a1);
}

// ---------------- final scores -> out (f32) --------------------------------
__launch_bounds__(256)
__global__ void k_score(const u16* __restrict__ feat, const float* __restrict__ q,
                        const float* __restrict__ v, float* __restrict__ outp) {
    __shared__ float qs[512];
    __shared__ float vs[512];
    __shared__ float sc[128];
    int bt = blockIdx.x;
    int b = bt >> 5;
    int tid = threadIdx.x;
    qs[tid] = q[bt * 512 + tid];
    qs[tid + 256] = q[bt * 512 + 256 + tid];
    vs[tid] = v[tid];
    vs[tid + 256] = v[tid + 256];
    __syncthreads();
    int lane = tid & 63, w = tid >> 6;
    int h0 = lane * 8;
    float qv[8], vv[8];
#pragma unroll
    for (int i = 0; i < 8; ++i) { qv[i] = qs[h0 + i]; vv[i] = vs[h0 + i]; }
    const u16* fb = feat + (size_t)b * 128 * 512;
    for (int i = 0; i < 32; ++i) {
        int n = w * 32 + i;
        uint4 fv = *(const uint4*)(fb + n * 512 + h0);
        float fr[8];
        fr[0] = b2f((u16)(fv.x & 0xFFFF)); fr[1] = b2f((u16)(fv.x >> 16));
        fr[2] = b2f((u16)(fv.y & 0xFFFF)); fr[3] = b2f((u16)(fv.y >> 16));
        fr[4] = b2f((u16)(fv.z & 0xFFFF)); fr[5] = b2f((u16)(fv.z >> 16));
        fr[6] = b2f((u16)(fv.w & 0xFFFF)); fr[7] = b2f((u16)(fv.w >> 16));
        float a = 0.f;
#pragma unroll
        for (int jj = 0; jj < 8; ++jj) a += fast_tanh(fr[jj] + qv[jj]) * vv[jj];
        for (int off = 1; off < 64; off <<= 1) a += __shfl_xor(a, off);
        if (lane == 0) sc[n] = a;
    }
    __syncthreads();
    if (tid < 128) outp[bt * 128 + tid] = sc[tid];
}

extern "C" void kernel_launch(void* const* d_in, const int* in_sizes, int n_in,
                              void* d_out, int out_size, void* d_ws, size_t ws_size,
                              hipStream_t stream) {
    (void)in_sizes; (void)n_in; (void)out_size; (void)ws_size;
    const float* attn_mem = (const float*)d_in[0];
    const int* mem_sizes = (const int*)d_in[1];
    const float* lstm_in = (const float*)d_in[2];
    const float* init_h = (const float*)d_in[3];
    const float* init_c = (const float*)d_in[4];
    const float* init_i = (const float*)d_in[5];
    const float* w_ih = (const float*)d_in[6];
    const float* w_hh = (const float*)d_in[7];
    const float* b_ih = (const float*)d_in[8];
    const float* b_hh = (const float*)d_in[9];
    const float* attn_wm = (const float*)d_in[10];
    const float* attn_wq = (const float*)d_in[11];
    const float* attn_v = (const float*)d_in[12];
    const float* hop_wm = (const float*)d_in[13];
    const float* hop_wq = (const float*)d_in[14];
    const float* hop_v = (const float*)d_in[15];
    float* out = (float*)d_out;

    char* ws = (char*)d_ws;
    size_t off = 0;
    auto alloc = [&](size_t bytes) {
        void* p = ws + off;
        off += (bytes + 255) & ~(size_t)255;
        return p;
    };
    // ~24.2 MB total (round-3 footprint was proven safe)
    u16* amem_bf = (u16*)alloc(4096 * 512 * 2);   // 4MB; reused as nq after attn_feat GEMM
    u16* xfull_bf = (u16*)alloc(1024 * 512 * 2);  // 1MB \ dead after xw GEMM -> qbuf (2MB)
    u16* wih_bf = (u16*)alloc(2048 * 512 * 2);    // 2MB /
    u16* whh_bf = (u16*)alloc(2048 * 512 * 2);    // 2MB
    u16* WmT_hop = (u16*)alloc(512 * 512 * 2);
    u16* WmT_attn = (u16*)alloc(512 * 512 * 2);
    u16* WqT_hop = (u16*)alloc(512 * 512 * 2);
    u16* WqT_attn = (u16*)alloc(512 * 512 * 2);
    float* xw = (float*)alloc(1024 * 2048 * 4);   // 8MB; first 4MB reused as attn_feat
    u16* hop_feat = (u16*)alloc(4096 * 512 * 2);  // 4MB
    u16* query = (u16*)alloc(1024 * 512 * 2);     // 1MB
    u16* hbuf = (u16*)alloc(2 * 32 * 512 * 2);    // 128KB double buffer
    unsigned int* bar = (unsigned int*)alloc(256);
    // aliases (stream-ordered):
    float* qbuf = (float*)xfull_bf;   // 2MB (xfull+wih dead after xw GEMM)
    u16* attn_feat = (u16*)xw;        // 4MB (xw dead after k_lstm)
    u16* nq = amem_bf;                // 1MB (amem dead after attn_feat GEMM)

    k_prep<<<5632, 256, 0, stream>>>(attn_mem, amem_bf, w_ih, wih_bf, w_hh, whh_bf,
                                     lstm_in, init_i, xfull_bf,
                                     attn_wm, hop_wm, hop_wq, attn_wq,
                                     WmT_attn, WmT_hop, WqT_hop, WqT_attn, bar);
    k_gemm<false><<<dim3(32, 16), 256, 0, stream>>>(xfull_bf, wih_bf, xw, 2048, b_ih, b_hh);
    k_gemm<true><<<dim3(8, 64), 256, 0, stream>>>(amem_bf, WmT_hop, hop_feat, 512, nullptr, nullptr);
    k_lstm<<<64, 256, 0, stream>>>(whh_bf, xw, init_h, init_c, query, hbuf, bar);
    k_gemm<true><<<dim3(8, 64), 256, 0, stream>>>(amem_bf, WmT_attn, attn_feat, 512, nullptr, nullptr);
    k_gemm<false><<<dim3(8, 16), 256, 0, stream>>>(query, WqT_hop, qbuf, 512, nullptr, nullptr);
    k_hop<<<1024, 256, 0, stream>>>(hop_feat, qbuf, hop_v, mem_sizes, nq);
    k_gemm<false><<<dim3(8, 16), 256, 0, stream>>>(nq, WqT_attn, qbuf, 512, nullptr, nullptr);
    k_score<<<1024, 256, 0, stream>>>(attn_feat, qbuf, attn_v, out);
}